// Round 4
// baseline (128.985 us; speedup 1.0000x reference)
//
#include <hip/hip_runtime.h>
#include <cmath>

// Kalman_Smooth_Gradient: B=4096 seqs, T=128 steps, 6-state EKF + RTS + loss.
// Round 19: r18 got filt to 48us (450 cyc/iter) but issue floor is ~150.
// At 1 wave/SIMD every dependent latency is exposed. The backward body's
// expensive chains (tanh exp->rcp, idet rcp, G matrix) depend ONLY on ring
// data available 2-4 iters early -> hoist them into a 2-iteration-ahead
// precompute stage (registers, Der ring depth 2). Serial consume stage
// shrinks to ~27 insts (ds->np/nv, M->GM->Ps, aq store). LDS ring deepened
// to 4. Reduce kernel: float4 loads (2 terms/load), 512 blocks.

namespace {

constexpr int B = 4096;
constexpr int T = 128;
constexpr int NT = B * 3;           // 12288 filter chains
constexpr int CPB = 64;             // chains (= threads) per block, one wave
constexpr int NBLK = NT / CPB;      // 192 blocks
constexpr int RBLK = 512;           // reduce kernel blocks
constexpr int RTH = 256;            // reduce kernel threads

constexpr float DTc     = 1.0f / 120.0f;
constexpr float TWO_PIc = 6.28318530717958647692f;
constexpr float PI_1_5  = 4.71238898038468985769f;
constexpr float INV_2PI = 0.15915494309189533577f;

__device__ __forceinline__ float frcp(float x) { return __builtin_amdgcn_rcpf(x); }

__device__ __forceinline__ float fast_tanh(float x) {
  float e = __expf(2.0f * x);
  return 1.0f - 2.0f * frcp(e + 1.0f);
}
__device__ __forceinline__ float sigmoidf(float x) {
  return frcp(1.0f + __expf(-x));
}

// Backward-pass precomputable quantities (depend only on filtered state at n,
// not on the serial smoother recursion): predictions tp/tv, predicted cov Pp,
// and the full smoother gain G.
struct Der {
  float tp, tv, Pp00, Pp01, Pp11;
  float G00, G01, G10, G11;
};

__device__ __forceinline__ Der derive(const float4 h4, const float f11,
                                      const float damping, const float friction,
                                      const float dcoef, const float q0,
                                      const float q1, const bool isTH) {
  Der d;
  const float fp = h4.x, fv = h4.y, f00 = h4.z, f01 = h4.w;
  float g;
  if (!isTH) {
    const float th = fast_tanh(100.0f * fv);
    d.tv = fv - DTc * (damping * fv + friction * th);
    g = 1.0f - DTc * (damping + 100.0f * friction * (1.0f - th * th));
  } else {
    d.tv = dcoef * fv;
    g = dcoef;
  }
  d.tp = fp + DTc * fv;
  const float u = f01 + DTc * f11;
  d.Pp00 = f00 + DTc * f01 + DTc * u + q0;
  d.Pp01 = g * u;
  d.Pp11 = g * (g * f11) + q1;
  // G = W Pp^{-1} (verified closed form; do not touch the algebra)
  const float idet = frcp(d.Pp00 * d.Pp11 - d.Pp01 * d.Pp01);
  const float c0 = d.Pp11 * idet, c1 = d.Pp01 * idet, c2 = d.Pp00 * idet;
  const float W01 = DTc * f00 + g * f01;
  const float W11 = DTc * f01 + g * f11;
  d.G00 = f00 * c0 - W01 * c1;
  d.G01 = W01 * c2 - f00 * c1;
  d.G10 = f01 * c0 - W11 * c1;
  d.G11 = W11 * c2 - f01 * c1;
  return d;
}

// ---------------------------------------------------------------------------
// z transpose: z[s][t][f] -> zt[f][t][s]. Block = 256 thr, tile = 64 seqs x
// 32 t x 3 f (24960 B LDS, stride-65 cols). Grid 256 blocks.
// ---------------------------------------------------------------------------
__global__ __launch_bounds__(256) void ztrans_kernel(
    const float* __restrict__ z, float* __restrict__ zt) {
  __shared__ float tile[96 * 65];
  const int tid = threadIdx.x;
  const int bs = blockIdx.x & 63;        // seq-chunk 0..63
  const int bt = blockIdx.x >> 6;        // t-chunk 0..3
  const int s0 = bs * 64, t0 = bt * 32;

  const float* __restrict__ zbase = z + (size_t)s0 * 384 + t0 * 3;
#pragma unroll
  for (int k = 0; k < 6; k++) {
    const int idx = tid + k * 256;       // 0..1535
    const int sl = idx / 24;             // seq-local 0..63
    const int c4 = idx - sl * 24;        // float4 col 0..23
    const float4 v4 = *(const float4*)(zbase + (size_t)sl * 384 + c4 * 4);
    tile[(c4 * 4 + 0) * 65 + sl] = v4.x;
    tile[(c4 * 4 + 1) * 65 + sl] = v4.y;
    tile[(c4 * 4 + 2) * 65 + sl] = v4.z;
    tile[(c4 * 4 + 3) * 65 + sl] = v4.w;
  }
  __syncthreads();
#pragma unroll
  for (int k = 0; k < 24; k++) {
    const int idx = tid + k * 256;       // 0..6143
    const int r  = idx >> 6;             // 0..95
    const int sl = idx & 63;
    const int fc = r >> 5;               // 0..2
    const int tl = r & 31;
    zt[((size_t)fc * T + t0 + tl) * B + s0 + sl] = tile[(tl * 3 + fc) * 65 + sl];
  }
}

// ---------------------------------------------------------------------------
// Main filter kernel. One wave per block; block b handles filter f = b>>6 for
// 64 consecutive seqs. hist4 (p,v,P00,P01) in LDS t=0..126 (t=127 in regs);
// P11 in LDS t=0..127. z from zt[f][t][seq]: coalesced 256 B loads, register
// ring depth 8. Backward: LDS rings depth 4 + Der precompute ring depth 2.
// aq: [f][T][B] float2 (a, a*e^2), valid n = 2..T-1.
// ---------------------------------------------------------------------------
__global__ __launch_bounds__(CPB, 1) void filt_kernel(
    const float* __restrict__ params, const float* __restrict__ covp,
    const float* __restrict__ init_states, const float* __restrict__ zt,
    float2* __restrict__ aq) {
  const int lane = threadIdx.x;            // 0..63
  const int blk  = blockIdx.x;             // 0..191
  const int f    = blk >> 6;               // filter 0=x,1=y,2=theta (uniform)
  const int seq  = ((blk & 63) << 6) + lane;

  __shared__ float4 h4s[127 * CPB];        // 130048 B, slot [t*64 + lane]
  __shared__ float  p11s[T * CPB];         //  32768 B, slot [t*64 + lane]

  // ---- shared scalars ----
  const float friction = (fast_tanh(params[0]) + 1.0f) * 0.01f;
  const float damping  = (fast_tanh(params[1]) + 1.0f) * 0.01f;
  float cp[7];
#pragma unroll
  for (int i = 0; i < 7; i++) cp[i] = sigmoidf(covp[i]);
  const float dcoef = 1.0f - DTc * damping;
  const bool isTH = (f == 2);              // wave-uniform branch
  const float q0 = isTH ? cp[5] : cp[3];
  const float q1 = isTH ? cp[6] : cp[4];
  const float r  = cp[f];

  // ---- init ----
  const int pidx = (f == 0) ? 0 : (f == 1) ? 1 : 4;
  const int vidx = (f == 0) ? 2 : (f == 1) ? 3 : 5;
  float p = init_states[seq * 6 + pidx];
  float v = init_states[seq * 6 + vidx];
  float P00 = 0.01f, P01 = 0.0f, P11 = 0.01f;

  // per-wave z stream: 64 consecutive floats per t (256 B coalesced).
  const float* __restrict__ ztf = zt + (size_t)f * T * B + seq;

  // =========================== forward ===========================
  float zr[8];
#pragma unroll
  for (int k = 0; k < 8; k++) zr[k] = ztf[(size_t)k * B];

#pragma unroll 8
  for (int t = 0; t < T; t++) {
    const float zc = zr[t & 7];
    const int tf = (t < T - 8) ? t + 8 : T - 1;      // clamped prefetch
    zr[t & 7] = ztf[(size_t)tf * B];

    float g, tv;
    if (!isTH) {
      const float th = fast_tanh(100.0f * v);
      tv = v - DTc * (damping * v + friction * th);
      g = 1.0f - DTc * (damping + 100.0f * friction * (1.0f - th * th));
    } else {
      tv = dcoef * v;
      g = dcoef;
    }
    const float tp = p + DTc * v;
    const float u = P01 + DTc * P11;
    const float Pp00 = P00 + DTc * P01 + DTc * u + q0;
    const float Pp01 = g * u;
    const float Pp11 = g * (g * P11) + q1;
    const float iS = frcp(Pp00 + r);
    const float K0 = Pp00 * iS;
    const float K1 = Pp01 * iS;
    float e = zc - tp;
    if (isTH) e = e - TWO_PIc * rintf(e * INV_2PI);  // _wrap
    p = tp + K0 * e;
    v = tv + K1 * e;
    const float om = 1.0f - K0;
    P00 = om * Pp00;
    P01 = om * Pp01;
    P11 = Pp11 - K1 * Pp01;

    if (t < 127) h4s[t * CPB + lane] = make_float4(p, v, P00, P01);
    p11s[t * CPB + lane] = P11;
  }

  // ---- terminal loss term n = T-1 (smoothed == filtered) ----
  {
    float e = ztf[(size_t)(T - 1) * B] - p;           // L2-hot
    if (isTH) {
      if (e >  PI_1_5) e -= TWO_PIc;
      if (e < -PI_1_5) e += TWO_PIc;
    }
    const float a = P00 + r;
    aq[((size_t)f * T + (T - 1)) * B + seq] = make_float2(a, a * e * e);
  }

  // =========================== backward ===========================
  // Same-wave, lane-private LDS dependence: no barrier needed.
  float sp_ = p, sv_ = v, Ps00 = P00, Ps01 = P01, Ps11 = P11;

  // Rings: h4/p11 LDS depth 4, z depth 8, Der precompute depth 2.
  float4 h4r[4];
  float  p11r[4];
  float  zrb[8];
#pragma unroll
  for (int k = 0; k < 4; k++) {
    h4r[k]  = h4s[(126 - k) * CPB + lane];
    p11r[k] = p11s[(126 - k) * CPB + lane];
  }
#pragma unroll
  for (int k = 0; k < 8; k++) zrb[k] = ztf[(size_t)(126 - k) * B];

  Der dr[2];
  dr[0] = derive(h4r[0], p11r[0], damping, friction, dcoef, q0, q1, isTH);
  dr[1] = derive(h4r[1], p11r[1], damping, friction, dcoef, q0, q1, isTH);

#pragma unroll 8
  for (int i = 0; i < 128; i++) {
    const int n = 126 - i;                   // 126 .. -1 (padded tail)
    const int s4 = i & 3;
    const int s8 = i & 7;
    const int s2 = i & 1;

    // ---- consume stage (minimal serial work) ----
    const Der d = dr[s2];
    const float4 h4 = h4r[s4];
    const float f11 = p11r[s4];
    const float zn_ = zrb[s8];
    const float fp = h4.x, fv = h4.y, f00 = h4.z, f01 = h4.w;

    const float ds0 = sp_ - d.tp, ds1 = sv_ - d.tv;
    const float np = fp + d.G00 * ds0 + d.G01 * ds1;
    const float nv = fv + d.G10 * ds0 + d.G11 * ds1;

    const float M00 = Ps00 - d.Pp00, M01 = Ps01 - d.Pp01, M11 = Ps11 - d.Pp11;
    const float GM00 = d.G00 * M00 + d.G01 * M01, GM01 = d.G00 * M01 + d.G01 * M11;
    const float GM10 = d.G10 * M00 + d.G11 * M01, GM11 = d.G10 * M01 + d.G11 * M11;
    Ps00 = f00 + GM00 * d.G00 + GM01 * d.G01;
    Ps01 = f01 + GM00 * d.G10 + GM01 * d.G11;
    Ps11 = f11 + GM10 * d.G10 + GM11 * d.G11;
    sp_ = np;
    sv_ = nv;

    if (n >= 2) {
      const float a = Ps00 + r;
      float e = zn_ - np;
      if (isTH) {
        if (e >  PI_1_5) e -= TWO_PIc;
        if (e < -PI_1_5) e += TWO_PIc;
      }
      aq[((size_t)f * T + n) * B + seq] = make_float2(a, a * e * e);
    }

    // ---- precompute stage for iter i+2 (independent of serial chain) ----
    dr[s2] = derive(h4r[(i + 2) & 3], p11r[(i + 2) & 3],
                    damping, friction, dcoef, q0, q1, isTH);

    // ---- ring refills (for iter i+4 / i+8) ----
    const int nl = (n >= 6) ? n - 4 : 2;     // clamped LDS prefetch target
    h4r[s4]  = h4s[nl * CPB + lane];
    p11r[s4] = p11s[nl * CPB + lane];
    const int nz = (n >= 10) ? n - 8 : 2;    // clamped z prefetch target
    zrb[s8] = ztf[(size_t)nz * B];
  }
}

// ---------------------------------------------------------------------------
// Reduce kernel: per (t, seq), det term = a_x*a_y*a_th (Sv diagonal) plus
// quadratic terms. float4 loads = two (t,s) terms per load per stream.
// ---------------------------------------------------------------------------
__global__ __launch_bounds__(RTH) void reduce_kernel(
    const float4* __restrict__ aq4, float* __restrict__ out) {
  const int tid = threadIdx.x;
  constexpr int HB = B / 2;            // 2048 float4 per (f,t) row
  constexpr int NTERM4 = 126 * HB;     // t = 2..127
  float part = 0.0f;
  for (int idx = blockIdx.x * RTH + tid; idx < NTERM4; idx += RTH * RBLK) {
    const int t = 2 + (idx >> 11);     // / 2048
    const int s4 = idx & (HB - 1);
    const float4 a0 = aq4[((size_t)0 * T + t) * HB + s4];
    const float4 a1 = aq4[((size_t)1 * T + t) * HB + s4];
    const float4 a2 = aq4[((size_t)2 * T + t) * HB + s4];
    part += a0.x * a1.x * a2.x + (a0.y + a1.y + a2.y);
    part += a0.z * a1.z * a2.z + (a0.w + a1.w + a2.w);
  }
  // wave reduce + cross-wave via LDS + one atomic per block
#pragma unroll
  for (int off = 32; off > 0; off >>= 1) part += __shfl_down(part, off);
  __shared__ float red[RTH / 64];
  if ((tid & 63) == 0) red[tid >> 6] = part;
  __syncthreads();
  if (tid == 0) {
    float s = 0.0f;
#pragma unroll
    for (int w = 0; w < RTH / 64; w++) s += red[w];
    atomicAdd(out, s);
  }
}

}  // namespace

extern "C" void kernel_launch(void* const* d_in, const int* in_sizes, int n_in,
                              void* d_out, int out_size, void* d_ws, size_t ws_size,
                              hipStream_t stream) {
  const float* params      = (const float*)d_in[0];
  const float* covp        = (const float*)d_in[1];
  const float* init_states = (const float*)d_in[2];
  const float* z           = (const float*)d_in[3];
  float* out = (float*)d_out;

  const size_t ztB = (size_t)T * NT * sizeof(float);    //  6.3 MB
  const size_t aqB = (size_t)T * NT * sizeof(float2);   // 12.6 MB
  const size_t needBytes = ztB + aqB;                   // 18.9 MB

  hipMemsetAsync(d_out, 0, sizeof(float), stream);

  if (ws_size >= needBytes) {
    float*  ztp = (float*)d_ws;
    float2* aqp = (float2*)((char*)d_ws + ztB);
    ztrans_kernel<<<256, 256, 0, stream>>>(z, ztp);
    filt_kernel<<<NBLK, CPB, 0, stream>>>(params, covp, init_states, ztp, aqp);
    reduce_kernel<<<RBLK, RTH, 0, stream>>>((const float4*)aqp, out);
  }
}

// Round 5
// 126.154 us; speedup vs baseline: 1.0224x; 1.0224x over previous
//
#include <hip/hip_runtime.h>
#include <cmath>

// Kalman_Smooth_Gradient: B=4096 seqs, T=128 steps, 6-state EKF + RTS + loss.
// Round 20: r19 proved the serial loops are ISSUE-BOUND (VALUBusy ~42% of
// active SIMD = ~84% of the 0.5 inst/cyc wave64 issue ceiling; r19's +22%
// insts -> +8% time). So: instruction diet.
//  1. Revert r19's derive-ahead ring (regression).
//  2. Offload bwd recompute to fwd: fwd iter t already computes tv,g,Pp00,
//     Pp11 = derive(n=t-1). Store as float4 stream tvg4[t][gid] (25MB ws,
//     coalesced, L2-resident per wave), read in bwd at slot n+1 via depth-4
//     ring. Bwd drops tanh/exp/rcp + Pp build (~15 VALU/iter); keeps only
//     u=f01+DT*f11, Pp01=g*u (bitwise-identical to fwd's values).
//  3. Loop splitting: main loops multiple-of-8 trip counts with UNCLAMPED
//     prefetch; compile-time fully-unrolled tails where clamps/guards fold.
//     Ring indices stay compile-time (rule: no runtime-indexed reg arrays).

namespace {

constexpr int B = 4096;
constexpr int T = 128;
constexpr int NT = B * 3;           // 12288 filter chains
constexpr int CPB = 64;             // chains (= threads) per block, one wave
constexpr int NBLK = NT / CPB;      // 192 blocks
constexpr int RBLK = 512;           // reduce kernel blocks
constexpr int RTH = 256;            // reduce kernel threads

constexpr float DTc     = 1.0f / 120.0f;
constexpr float TWO_PIc = 6.28318530717958647692f;
constexpr float PI_1_5  = 4.71238898038468985769f;
constexpr float INV_2PI = 0.15915494309189533577f;

__device__ __forceinline__ float frcp(float x) { return __builtin_amdgcn_rcpf(x); }

__device__ __forceinline__ float fast_tanh(float x) {
  float e = __expf(2.0f * x);
  return 1.0f - 2.0f * frcp(e + 1.0f);
}
__device__ __forceinline__ float sigmoidf(float x) {
  return frcp(1.0f + __expf(-x));
}

// ---------------------------------------------------------------------------
// z transpose: z[s][t][f] -> zt[f][t][s]. Block = 256 thr, tile = 64 seqs x
// 32 t x 3 f (24960 B LDS, stride-65 cols). Grid 256 blocks.
// ---------------------------------------------------------------------------
__global__ __launch_bounds__(256) void ztrans_kernel(
    const float* __restrict__ z, float* __restrict__ zt) {
  __shared__ float tile[96 * 65];
  const int tid = threadIdx.x;
  const int bs = blockIdx.x & 63;        // seq-chunk 0..63
  const int bt = blockIdx.x >> 6;        // t-chunk 0..3
  const int s0 = bs * 64, t0 = bt * 32;

  const float* __restrict__ zbase = z + (size_t)s0 * 384 + t0 * 3;
#pragma unroll
  for (int k = 0; k < 6; k++) {
    const int idx = tid + k * 256;       // 0..1535
    const int sl = idx / 24;             // seq-local 0..63
    const int c4 = idx - sl * 24;        // float4 col 0..23
    const float4 v4 = *(const float4*)(zbase + (size_t)sl * 384 + c4 * 4);
    tile[(c4 * 4 + 0) * 65 + sl] = v4.x;
    tile[(c4 * 4 + 1) * 65 + sl] = v4.y;
    tile[(c4 * 4 + 2) * 65 + sl] = v4.z;
    tile[(c4 * 4 + 3) * 65 + sl] = v4.w;
  }
  __syncthreads();
#pragma unroll
  for (int k = 0; k < 24; k++) {
    const int idx = tid + k * 256;       // 0..6143
    const int r  = idx >> 6;             // 0..95
    const int sl = idx & 63;
    const int fc = r >> 5;               // 0..2
    const int tl = r & 31;
    zt[((size_t)fc * T + t0 + tl) * B + s0 + sl] = tile[(tl * 3 + fc) * 65 + sl];
  }
}

// ---------------------------------------------------------------------------
// Main filter kernel. One wave per block; block b handles filter f = b>>6 for
// 64 consecutive seqs. LDS: hist4 (p,v,P00,P01) t=0..126 + P11 t=0..127.
// Global: tvg4[t][NT] float4 (tv,g,Pp00,Pp11) = derive(t-1), written in fwd,
// read in bwd at slot n+1 (depth-4 ring). z from zt[f][t][seq] (depth-8 ring).
// aq: [f][T][B] float2 (a, a*e^2), valid n = 2..T-1.
// ---------------------------------------------------------------------------
__global__ __launch_bounds__(CPB, 1) void filt_kernel(
    const float* __restrict__ params, const float* __restrict__ covp,
    const float* __restrict__ init_states, const float* __restrict__ zt,
    float4* __restrict__ tvg4, float2* __restrict__ aq) {
  const int lane = threadIdx.x;            // 0..63
  const int blk  = blockIdx.x;             // 0..191
  const int f    = blk >> 6;               // filter 0=x,1=y,2=theta (uniform)
  const int seq  = ((blk & 63) << 6) + lane;
  const int gid  = blk * CPB + lane;       // == f*B + seq

  __shared__ float4 h4s[127 * CPB];        // 130048 B, slot [t*64 + lane]
  __shared__ float  p11s[T * CPB];         //  32768 B, slot [t*64 + lane]

  // ---- shared scalars ----
  const float friction = (fast_tanh(params[0]) + 1.0f) * 0.01f;
  const float damping  = (fast_tanh(params[1]) + 1.0f) * 0.01f;
  float cp[7];
#pragma unroll
  for (int i = 0; i < 7; i++) cp[i] = sigmoidf(covp[i]);
  const float dcoef = 1.0f - DTc * damping;
  const bool isTH = (f == 2);              // wave-uniform branch
  const float q0 = isTH ? cp[5] : cp[3];
  const float q1 = isTH ? cp[6] : cp[4];
  const float r  = cp[f];

  // ---- init ----
  const int pidx = (f == 0) ? 0 : (f == 1) ? 1 : 4;
  const int vidx = (f == 0) ? 2 : (f == 1) ? 3 : 5;
  float p = init_states[seq * 6 + pidx];
  float v = init_states[seq * 6 + vidx];
  float P00 = 0.01f, P01 = 0.0f, P11 = 0.01f;

  const float* __restrict__ ztf = zt + (size_t)f * T * B + seq;

  // =========================== forward ===========================
  float zr[8];
#pragma unroll
  for (int k = 0; k < 8; k++) zr[k] = ztf[(size_t)k * B];
  float zlast = 0.0f;

#define FWD_BODY(t, REFILL)                                                  \
  {                                                                          \
    const float zc = zr[(t) & 7];                                            \
    if (REFILL) zr[(t) & 7] = ztf[(size_t)((t) + 8) * B];                    \
    float g, tv;                                                             \
    if (!isTH) {                                                             \
      const float th = fast_tanh(100.0f * v);                                \
      tv = v - DTc * (damping * v + friction * th);                          \
      g = 1.0f - DTc * (damping + 100.0f * friction * (1.0f - th * th));     \
    } else {                                                                 \
      tv = dcoef * v;                                                        \
      g = dcoef;                                                             \
    }                                                                        \
    const float tp = p + DTc * v;                                            \
    const float u = P01 + DTc * P11;                                         \
    const float Pp00 = P00 + DTc * P01 + DTc * u + q0;                       \
    const float Pp01 = g * u;                                                \
    const float Pp11 = g * (g * P11) + q1;                                   \
    tvg4[(size_t)(t) * NT + gid] = make_float4(tv, g, Pp00, Pp11);           \
    const float iS = frcp(Pp00 + r);                                         \
    const float K0 = Pp00 * iS;                                              \
    const float K1 = Pp01 * iS;                                              \
    float e = zc - tp;                                                       \
    if (isTH) e = e - TWO_PIc * rintf(e * INV_2PI);                          \
    p = tp + K0 * e;                                                         \
    v = tv + K1 * e;                                                         \
    const float om = 1.0f - K0;                                              \
    P00 = om * Pp00;                                                         \
    P01 = om * Pp01;                                                         \
    P11 = Pp11 - K1 * Pp01;                                                  \
    if ((t) < 127) h4s[(t) * CPB + lane] = make_float4(p, v, P00, P01);      \
    p11s[(t) * CPB + lane] = P11;                                            \
    if ((t) == 127) zlast = zc;                                              \
  }

#pragma unroll 8
  for (int t = 0; t < 120; t++) FWD_BODY(t, true)
#pragma unroll
  for (int t = 120; t < 128; t++) FWD_BODY(t, false)
#undef FWD_BODY

  // ---- terminal loss term n = T-1 (smoothed == filtered) ----
  {
    float e = zlast - p;
    if (isTH) {
      if (e >  PI_1_5) e -= TWO_PIc;
      if (e < -PI_1_5) e += TWO_PIc;
    }
    const float a = P00 + r;
    aq[((size_t)f * T + (T - 1)) * B + seq] = make_float2(a, a * e * e);
  }

  // =========================== backward ===========================
  // Same-wave, lane-private LDS dependence: no barrier needed.
  float sp_ = p, sv_ = v, Ps00 = P00, Ps01 = P01, Ps11 = P11;

  // Rings: h4/p11/dvr depth 4, z depth 8. dvr slot for step n = tvg4[n+1].
  float4 h4r[4], dvr[4];
  float  p11r[4];
  float  zrb[8];
#pragma unroll
  for (int k = 0; k < 4; k++) {
    h4r[k]  = h4s[(126 - k) * CPB + lane];
    p11r[k] = p11s[(126 - k) * CPB + lane];
    dvr[k]  = tvg4[(size_t)(127 - k) * NT + gid];
  }
#pragma unroll
  for (int k = 0; k < 8; k++) zrb[k] = ztf[(size_t)(126 - k) * B];

#define BWD_BODY(i, RH4, RDV, RZ)                                            \
  {                                                                          \
    const int n = 126 - (i);                                                 \
    const float4 h4 = h4r[(i) & 3];                                          \
    const float f11 = p11r[(i) & 3];                                         \
    const float4 d4 = dvr[(i) & 3];                                          \
    const float zn_ = zrb[(i) & 7];                                          \
    if (RH4) {                                                               \
      const int nl = (n >= 6) ? n - 4 : 2;                                   \
      h4r[(i) & 3]  = h4s[nl * CPB + lane];                                  \
      p11r[(i) & 3] = p11s[nl * CPB + lane];                                 \
    }                                                                        \
    if (RDV) {                                                               \
      const int nd = (n >= 6) ? n - 3 : 3;                                   \
      dvr[(i) & 3] = tvg4[(size_t)nd * NT + gid];                            \
    }                                                                        \
    if (RZ) {                                                                \
      const int nz = (n >= 10) ? n - 8 : 2;                                  \
      zrb[(i) & 7] = ztf[(size_t)nz * B];                                    \
    }                                                                        \
    const float fp = h4.x, fv = h4.y, f00 = h4.z, f01 = h4.w;                \
    const float tv = d4.x, g = d4.y, Pp00 = d4.z, Pp11 = d4.w;               \
    const float tp = fp + DTc * fv;                                          \
    const float u = f01 + DTc * f11;                                         \
    const float Pp01 = g * u;                                                \
    const float dett = Pp00 * Pp11 - Pp01 * Pp01;                            \
    const float idet = frcp(dett);                                           \
    const float c0 = Pp11 * idet, c1 = Pp01 * idet, c2 = Pp00 * idet;        \
    const float W01 = DTc * f00 + g * f01;                                   \
    const float W11 = DTc * f01 + g * f11;                                   \
    const float G00 = f00 * c0 - W01 * c1;                                   \
    const float G01 = W01 * c2 - f00 * c1;                                   \
    const float G10 = f01 * c0 - W11 * c1;                                   \
    const float G11 = W11 * c2 - f01 * c1;                                   \
    const float ds0 = sp_ - tp, ds1 = sv_ - tv;                              \
    const float np = fp + G00 * ds0 + G01 * ds1;                             \
    const float nv = fv + G10 * ds0 + G11 * ds1;                             \
    const float M00 = Ps00 - Pp00, M01 = Ps01 - Pp01, M11 = Ps11 - Pp11;     \
    const float GM00 = G00 * M00 + G01 * M01, GM01 = G00 * M01 + G01 * M11;  \
    const float GM10 = G10 * M00 + G11 * M01, GM11 = G10 * M01 + G11 * M11;  \
    Ps00 = f00 + GM00 * G00 + GM01 * G01;                                    \
    Ps01 = f01 + GM00 * G10 + GM01 * G11;                                    \
    Ps11 = f11 + GM10 * G10 + GM11 * G11;                                    \
    sp_ = np;                                                                \
    sv_ = nv;                                                                \
    const float a = Ps00 + r;                                                \
    float e = zn_ - np;                                                      \
    if (isTH) {                                                              \
      if (e >  PI_1_5) e -= TWO_PIc;                                         \
      if (e < -PI_1_5) e += TWO_PIc;                                         \
    }                                                                        \
    aq[((size_t)f * T + n) * B + seq] = make_float2(a, a * e * e);           \
  }

  // main: i = 0..111 (n = 126..15): all prefetch targets unclamped-valid.
#pragma unroll 8
  for (int i = 0; i < 112; i++) BWD_BODY(i, true, true, true)
  // tail: i = 112..124 (n = 14..2): full unroll, clamps fold at compile time;
  // refills only while a future iteration will consume them.
#pragma unroll
  for (int i = 112; i < 125; i++)
    BWD_BODY(i, (126 - i) >= 6, (126 - i) >= 6, (126 - i) >= 10)
#undef BWD_BODY
}

// ---------------------------------------------------------------------------
// Reduce kernel: per (t, seq), det term = a_x*a_y*a_th (Sv diagonal) plus
// quadratic terms. float4 loads = two (t,s) terms per load per stream.
// ---------------------------------------------------------------------------
__global__ __launch_bounds__(RTH) void reduce_kernel(
    const float4* __restrict__ aq4, float* __restrict__ out) {
  const int tid = threadIdx.x;
  constexpr int HB = B / 2;            // 2048 float4 per (f,t) row
  constexpr int NTERM4 = 126 * HB;     // t = 2..127
  float part = 0.0f;
  for (int idx = blockIdx.x * RTH + tid; idx < NTERM4; idx += RTH * RBLK) {
    const int t = 2 + (idx >> 11);     // / 2048
    const int s4 = idx & (HB - 1);
    const float4 a0 = aq4[((size_t)0 * T + t) * HB + s4];
    const float4 a1 = aq4[((size_t)1 * T + t) * HB + s4];
    const float4 a2 = aq4[((size_t)2 * T + t) * HB + s4];
    part += a0.x * a1.x * a2.x + (a0.y + a1.y + a2.y);
    part += a0.z * a1.z * a2.z + (a0.w + a1.w + a2.w);
  }
  // wave reduce + cross-wave via LDS + one atomic per block
#pragma unroll
  for (int off = 32; off > 0; off >>= 1) part += __shfl_down(part, off);
  __shared__ float red[RTH / 64];
  if ((tid & 63) == 0) red[tid >> 6] = part;
  __syncthreads();
  if (tid == 0) {
    float s = 0.0f;
#pragma unroll
    for (int w = 0; w < RTH / 64; w++) s += red[w];
    atomicAdd(out, s);
  }
}

}  // namespace

extern "C" void kernel_launch(void* const* d_in, const int* in_sizes, int n_in,
                              void* d_out, int out_size, void* d_ws, size_t ws_size,
                              hipStream_t stream) {
  const float* params      = (const float*)d_in[0];
  const float* covp        = (const float*)d_in[1];
  const float* init_states = (const float*)d_in[2];
  const float* z           = (const float*)d_in[3];
  float* out = (float*)d_out;

  const size_t ztB   = (size_t)T * NT * sizeof(float);    //  6.3 MB
  const size_t aqB   = (size_t)T * NT * sizeof(float2);   // 12.6 MB
  const size_t tvgB  = (size_t)T * NT * sizeof(float4);   // 25.2 MB
  const size_t needBytes = ztB + aqB + tvgB;              // 44.0 MB

  hipMemsetAsync(d_out, 0, sizeof(float), stream);

  if (ws_size >= needBytes) {
    float*  ztp  = (float*)d_ws;
    float2* aqp  = (float2*)((char*)d_ws + ztB);
    float4* tvgp = (float4*)((char*)d_ws + ztB + aqB);
    ztrans_kernel<<<256, 256, 0, stream>>>(z, ztp);
    filt_kernel<<<NBLK, CPB, 0, stream>>>(params, covp, init_states, ztp,
                                          tvgp, aqp);
    reduce_kernel<<<RBLK, RTH, 0, stream>>>((const float4*)aqp, out);
  }
}